// Round 20
// baseline (166.558 us; speedup 1.0000x reference)
//
#include <hip/hip_runtime.h>
#include <math.h>

#define T_SEQ 2048
#define C_DIM 1024
#define NHEAD 16
#define HDIM 64
#define M_ROWS 4096   // B*T
#define N_QKV 3072    // 3*C
#define CHB 24576     // img bytes per 64-key chunk: khi 8K | klo 8K | vT 8K

typedef __attribute__((ext_vector_type(8))) short short8;   // 8 bf16 (4 VGPR)
typedef __attribute__((ext_vector_type(4))) float f32x4;    // MFMA C/D
typedef unsigned short ushort_t;

__device__ inline unsigned short f2bf(float x) {            // RNE f32->bf16
  union { float f; unsigned u; } v; v.f = x;
  unsigned r = v.u + 0x7FFF + ((v.u >> 16) & 1);
  return (unsigned short)(r >> 16);
}
__device__ inline float bf2f(unsigned short h) {
  union { unsigned u; float f; } v; v.u = ((unsigned)h) << 16; return v.f;
}
__device__ inline unsigned fbits(float x) {
  union { float f; unsigned u; } v; v.f = x; return v.u;
}

// async global->LDS, 16B per lane; LDS dest = wave-uniform base + lane*16
__device__ __forceinline__ void gll16(const char* g, char* l) {
  __builtin_amdgcn_global_load_lds(
      (const __attribute__((address_space(1))) unsigned*)g,
      (__attribute__((address_space(3))) unsigned*)l, 16, 0, 0);
}

// ---------------- fused abs-sum pass (both weights, one launch) -------------
__global__ __launch_bounds__(256) void abs2_k(const float* __restrict__ w_qkv,
                                              const float* __restrict__ w_out,
                                              float* __restrict__ part) {
  __shared__ float red[256];
  const int bx = blockIdx.x;
  const float* w;
  int n, nblk, bi;
  if (bx < 256) { w = w_qkv; n = N_QKV * C_DIM; nblk = 256; bi = bx; }
  else          { w = w_out; n = C_DIM * C_DIM; nblk = 128; bi = bx - 256; }
  float s = 0.f;
  for (int i = bi * 256 + threadIdx.x; i < n; i += nblk * 256)
    s += fabsf(w[i]);
  red[threadIdx.x] = s;
  __syncthreads();
  for (int st = 128; st > 0; st >>= 1) {
    if ((int)threadIdx.x < st) red[threadIdx.x] += red[threadIdx.x + st];
    __syncthreads();
  }
  if (threadIdx.x == 0) part[bx] = red[0];
}

__global__ __launch_bounds__(256) void finalize2_k(const float* __restrict__ part,
                                                   float* __restrict__ scales) {
  __shared__ float red[256];
  const int bx = blockIdx.x;
  const int lim = (bx == 0) ? 256 : 128;
  red[threadIdx.x] = ((int)threadIdx.x < lim) ? part[bx * 256 + threadIdx.x] : 0.f;
  __syncthreads();
  for (int st = 128; st > 0; st >>= 1) {
    if ((int)threadIdx.x < st) red[threadIdx.x] += red[threadIdx.x + st];
    __syncthreads();
  }
  if (threadIdx.x == 0) {
    float n = (bx == 0) ? (float)(N_QKV * C_DIM) : (float)(C_DIM * C_DIM);
    scales[bx] = fmaxf(red[0] / n, 1e-8f);
  }
}

// ---------------- fused elementwise: ternarize both weights + split x -------
__global__ __launch_bounds__(256) void prep_elem_k(const float* __restrict__ w_qkv,
                                                   const float* __restrict__ w_out,
                                                   const float* __restrict__ x,
                                                   ushort_t* __restrict__ wt_qkv,
                                                   ushort_t* __restrict__ wt_out,
                                                   ushort_t* __restrict__ xh,
                                                   ushort_t* __restrict__ xl,
                                                   const float* __restrict__ scales) {
  const int bx = blockIdx.x;
  if (bx < 12288) {
    const int i = bx * 256 + threadIdx.x;
    const float s = scales[0];
    const float t = rintf(w_qkv[i] / s);
    wt_qkv[i] = f2bf(fminf(1.f, fmaxf(-1.f, t)));
  } else if (bx < 16384) {
    const int i = (bx - 12288) * 256 + threadIdx.x;
    const float s = scales[1];
    const float t = rintf(w_out[i] / s);
    wt_out[i] = f2bf(fminf(1.f, fmaxf(-1.f, t)));
  } else {
    const int i = (bx - 16384) * 256 + threadIdx.x;     // float4 index
    const float4 v = ((const float4*)x)[i];
    const float vv[4] = {v.x, v.y, v.z, v.w};
    ushort_t hh[4], ll[4];
#pragma unroll
    for (int j = 0; j < 4; ++j) {
      hh[j] = f2bf(vv[j]);
      ll[j] = f2bf(vv[j] - bf2f(hh[j]));
    }
    ((ushort4*)xh)[i] = make_ushort4(hh[0], hh[1], hh[2], hh[3]);
    ((ushort4*)xl)[i] = make_ushort4(ll[0], ll[1], ll[2], ll[3]);
  }
}

// ---------------- fused qkv GEMM: hi/lo MFMA + direct img epilogue ----------
__global__ __launch_bounds__(256) void gemm_qkv_k(const ushort_t* __restrict__ Ah,
                                                  const ushort_t* __restrict__ Al,
                                                  const ushort_t* __restrict__ Bw,
                                                  float* __restrict__ qG,
                                                  char* __restrict__ img,
                                                  int Kd) {
  __shared__ __align__(16) char lds[49152];   // Ah 16K | Al 16K | B 16K
  const int tid = threadIdx.x;
  const int bm = blockIdx.y << 7, bn = blockIdx.x << 7;
  const int w = tid >> 6, lane = tid & 63;
  const int wm = (w >> 1) << 6, wn = (w & 1) << 6;
  const int fr = lane & 15, fc = lane >> 4;

  int srow[4], scol[4];
#pragma unroll
  for (int i = 0; i < 4; ++i) {
    const int slot = i * 256 + tid;
    const int r = slot >> 3, s = slot & 7;
    srow[i] = r;
    scol[i] = (s ^ (r & 7)) << 3;            // pre-swizzled source column
  }

  f32x4 acc[4][4];
  const f32x4 z = {0.f, 0.f, 0.f, 0.f};
#pragma unroll
  for (int i = 0; i < 4; ++i)
#pragma unroll
    for (int j = 0; j < 4; ++j) acc[i][j] = z;

  for (int k0 = 0; k0 < Kd; k0 += 64) {
    __syncthreads();
#pragma unroll
    for (int i = 0; i < 4; ++i) {
      const int d16 = (i * 256 + tid) * 16;
      const size_t ga = (size_t)(bm + srow[i]) * Kd + k0 + scol[i];
      const size_t gb = (size_t)(bn + srow[i]) * Kd + k0 + scol[i];
      gll16((const char*)(Ah + ga), lds + d16);
      gll16((const char*)(Al + ga), lds + 16384 + d16);
      gll16((const char*)(Bw + gb), lds + 32768 + d16);
    }
    __syncthreads();
#pragma unroll
    for (int ks = 0; ks < 2; ++ks) {
      short8 af[4], lf[4], bf[4];
#pragma unroll
      for (int i = 0; i < 4; ++i) {
        const int ra = wm + i * 16 + fr;
        const int ca = (ks * 64 + fc * 16) ^ ((ra & 7) << 4);
        af[i] = *(const short8*)(lds + ra * 128 + ca);
        lf[i] = *(const short8*)(lds + 16384 + ra * 128 + ca);
        const int rb = wn + i * 16 + fr;
        const int cbb = (ks * 64 + fc * 16) ^ ((rb & 7) << 4);
        bf[i] = *(const short8*)(lds + 32768 + rb * 128 + cbb);
      }
#pragma unroll
      for (int i = 0; i < 4; ++i)
#pragma unroll
        for (int j = 0; j < 4; ++j) {
          acc[i][j] = __builtin_amdgcn_mfma_f32_16x16x32_bf16(af[i], bf[j], acc[i][j], 0, 0, 0);
          acc[i][j] = __builtin_amdgcn_mfma_f32_16x16x32_bf16(lf[i], bf[j], acc[i][j], 0, 0, 0);
        }
    }
  }

  // ---- epilogue (block-uniform routing on bn) ----
  if (bn < 1024) {
    // Q: fp32 [4096][1024]
#pragma unroll
    for (int i = 0; i < 4; ++i)
#pragma unroll
      for (int j = 0; j < 4; ++j) {
        float* cp = qG + (size_t)(bm + wm + i * 16 + fc * 4) * 1024 + bn + wn + j * 16 + fr;
#pragma unroll
        for (int r = 0; r < 4; ++r) cp[(size_t)r * 1024] = acc[i][j][r];
      }
  } else if (bn < 2048) {
    // K -> img hi/lo: off = key*128 + ((d*2)^((key&7)<<4))
#pragma unroll
    for (int i = 0; i < 4; ++i) {
      const int row0 = bm + wm + i * 16 + fc * 4;
#pragma unroll
      for (int r = 0; r < 4; ++r) {
        const int row = row0 + r;
        const int bb = row >> 11, t = row & 2047;
        const int c = t >> 6, key = t & 63;
        const int ksw = (key & 7) << 4;
        char* const igb = img + ((size_t)(bb << 4) * 32) * CHB + (size_t)c * CHB + key * 128;
#pragma unroll
        for (int j = 0; j < 4; ++j) {
          const int col = bn + wn + j * 16 + fr - 1024;
          const int h = col >> 6, d = col & 63;
          char* const ig = igb + (size_t)(h * 32) * CHB;
          const float v = acc[i][j][r];
          const unsigned short hi = f2bf(v);
          const unsigned short lo = f2bf(v - bf2f(hi));
          const int off = (d * 2) ^ ksw;
          *(ushort_t*)(ig + off) = hi;
          *(ushort_t*)(ig + 8192 + off) = lo;
        }
      }
    }
  } else {
    // V -> img vT: off = 16384 + d*128 + ((key*2)^((d&7)<<4))
#pragma unroll
    for (int i = 0; i < 4; ++i) {
      const int row0 = bm + wm + i * 16 + fc * 4;
#pragma unroll
      for (int r = 0; r < 4; ++r) {
        const int row = row0 + r;
        const int bb = row >> 11, t = row & 2047;
        const int c = t >> 6, key = t & 63;
        char* const igb = img + ((size_t)(bb << 4) * 32) * CHB + (size_t)c * CHB + 16384;
#pragma unroll
        for (int j = 0; j < 4; ++j) {
          const int col = bn + wn + j * 16 + fr - 2048;
          const int h = col >> 6, d = col & 63;
          char* const ig = igb + (size_t)(h * 32) * CHB;
          const int off = d * 128 + ((key * 2) ^ ((d & 7) << 4));
          *(ushort_t*)(ig + off) = f2bf(acc[i][j][r]);
        }
      }
    }
  }
}

// ---------------- out projection GEMM: 64x128 tile, 2 blocks/CU -------------
__global__ __launch_bounds__(256) void gemm_out_k(const ushort_t* __restrict__ A,
                                                  const ushort_t* __restrict__ Bw,
                                                  float* __restrict__ C,
                                                  int Nd, int Kd) {
  __shared__ __align__(16) char lds[24576];   // A 8K | B 16K
  const int tid = threadIdx.x;
  const int bm = blockIdx.y << 6, bn = blockIdx.x << 7;
  const int w = tid >> 6, lane = tid & 63;
  const int wn = w << 5;                      // wave covers 32 N-cols
  const int fr = lane & 15, fc = lane >> 4;

  f32x4 acc[4][2];
  const f32x4 z = {0.f, 0.f, 0.f, 0.f};
#pragma unroll
  for (int i = 0; i < 4; ++i)
#pragma unroll
    for (int j = 0; j < 2; ++j) acc[i][j] = z;

  for (int k0 = 0; k0 < Kd; k0 += 64) {
    __syncthreads();
#pragma unroll
    for (int i = 0; i < 2; ++i) {            // A: 64 rows
      const int slot = i * 256 + tid;
      const int r = slot >> 3, s = slot & 7;
      gll16((const char*)(A + (size_t)(bm + r) * Kd + k0 + ((s ^ (r & 7)) << 3)),
            lds + slot * 16);
    }
#pragma unroll
    for (int i = 0; i < 4; ++i) {            // B: 128 rows
      const int slot = i * 256 + tid;
      const int r = slot >> 3, s = slot & 7;
      gll16((const char*)(Bw + (size_t)(bn + r) * Kd + k0 + ((s ^ (r & 7)) << 3)),
            lds + 8192 + slot * 16);
    }
    __syncthreads();
#pragma unroll
    for (int ks = 0; ks < 2; ++ks) {
      short8 af[4], bf[2];
#pragma unroll
      for (int i = 0; i < 4; ++i) {
        const int ra = i * 16 + fr;
        af[i] = *(const short8*)(lds + ra * 128 + ((ks * 64 + fc * 16) ^ ((ra & 7) << 4)));
      }
#pragma unroll
      for (int j = 0; j < 2; ++j) {
        const int rb = wn + j * 16 + fr;
        bf[j] = *(const short8*)(lds + 8192 + rb * 128 + ((ks * 64 + fc * 16) ^ ((rb & 7) << 4)));
      }
#pragma unroll
      for (int i = 0; i < 4; ++i)
#pragma unroll
        for (int j = 0; j < 2; ++j)
          acc[i][j] = __builtin_amdgcn_mfma_f32_16x16x32_bf16(af[i], bf[j], acc[i][j], 0, 0, 0);
    }
  }
#pragma unroll
  for (int i = 0; i < 4; ++i)
#pragma unroll
    for (int j = 0; j < 2; ++j) {
      float* cp = C + (size_t)(bm + i * 16 + fc * 4) * Nd + bn + wn + j * 16 + fr;
#pragma unroll
      for (int r = 0; r < 4; ++r) cp[(size_t)r * Nd] = acc[i][j][r];
    }
}

// ---------------- split-K swapped-QK attention, 64-key chunks ---------------
// Grid 2048: (qt desc LPT, parity s, gg). Parity s does chunks c≡s (mod 2).
// 24KB single-buffer; VGPR ~76 -> 6 blocks/CU capacity, ~2x R19 concurrency.
// Partials: unnormalized bf16 O + group-uniform fp32 (m,l); merged by merge_k.
struct TS2 { f32x4 O[4]; float m; float l; };

__device__ __forceinline__ void post_qk(f32x4* s4, TS2& st, const char* vTp,
                                        const bool diag, const int w, const int lg,
                                        const int lr, const int sh0, const int sh1) {
  if (diag) {
#pragma unroll
    for (int f = 0; f < 4; ++f)
#pragma unroll
      for (int r = 0; r < 4; ++r)
        if (16 * f + 4 * lg + r > w * 16 + lr) s4[f][r] = -1e30f;
  }
  float mc = fmaxf(fmaxf(s4[0][0], s4[0][1]), fmaxf(s4[0][2], s4[0][3]));
#pragma unroll
  for (int f = 1; f < 4; ++f)
#pragma unroll
    for (int r = 0; r < 4; ++r) mc = fmaxf(mc, s4[f][r]);
  if (__any(mc > st.m + 11.5f)) {          // defer-max (log2 units)
    mc = fmaxf(mc, __shfl_xor(mc, 16));
    mc = fmaxf(mc, __shfl_xor(mc, 32));
    const float mn = fmaxf(st.m, mc);
    const float rs = exp2f(st.m - mn);
    st.m = mn;
    st.l *= rs;
#pragma unroll
    for (int n = 0; n < 4; ++n)
#pragma unroll
      for (int r = 0; r < 4; ++r) st.O[n][r] *= rs;
  }
#pragma unroll
  for (int f = 0; f < 4; ++f)
#pragma unroll
    for (int r = 0; r < 4; ++r) s4[f][r] = exp2f(s4[f][r] - st.m);
#pragma unroll
  for (int f = 0; f < 4; ++f)
    st.l += (s4[f][0] + s4[f][1]) + (s4[f][2] + s4[f][3]);

  // pack adjacent key-pairs: D[f][rp] = bf16(p[2rp]) | bf16(p[2rp+1])<<16
  unsigned D[4][2];
#pragma unroll
  for (int f = 0; f < 4; ++f)
#pragma unroll
    for (int rp = 0; rp < 2; ++rp)
      D[f][rp] = (fbits(s4[f][2 * rp + 1]) & 0xFFFF0000u) | (fbits(s4[f][2 * rp]) >> 16);

  // gather group's P into B-operand order
  int g[4][2][2];
#pragma unroll
  for (int f = 0; f < 4; ++f)
#pragma unroll
    for (int rp = 0; rp < 2; ++rp) {
      g[f][rp][0] = __shfl((int)D[f][rp], sh0, 64);
      g[f][rp][1] = __shfl((int)D[f][rp], sh1, 64);
    }
  const bool hi2 = (lg & 2) != 0;
  union PB { int4 i; short8 s; } pb0, pb1;
  pb0.i.x = hi2 ? g[1][0][0] : g[0][0][0];
  pb0.i.y = hi2 ? g[1][1][0] : g[0][1][0];
  pb0.i.z = hi2 ? g[1][0][1] : g[0][0][1];
  pb0.i.w = hi2 ? g[1][1][1] : g[0][1][1];
  pb1.i.x = hi2 ? g[3][0][0] : g[2][0][0];
  pb1.i.y = hi2 ? g[3][1][0] : g[2][1][0];
  pb1.i.z = hi2 ? g[3][0][1] : g[2][0][1];
  pb1.i.w = hi2 ? g[3][1][1] : g[2][1][1];

  // PV: O^T[d][q] = mfma(A=V^T rows 16n+lr, B=P^T)
  const int swz = (lr & 7) << 4;
#pragma unroll
  for (int n = 0; n < 4; ++n) {
    const int d = 16 * n + lr;
    const short8 va0 = *(const short8*)(vTp + d * 128 + ((lg * 16) ^ swz));
    st.O[n] = __builtin_amdgcn_mfma_f32_16x16x32_bf16(va0, pb0.s, st.O[n], 0, 0, 0);
    const short8 va1 = *(const short8*)(vTp + d * 128 + ((64 + lg * 16) ^ swz));
    st.O[n] = __builtin_amdgcn_mfma_f32_16x16x32_bf16(va1, pb1.s, st.O[n], 0, 0, 0);
  }
}

__device__ __forceinline__ void load_q(const float* qG, int b, int qt, int h,
                                       int w, int lg, int lr,
                                       short8* qh, short8* ql) {
  const float* qrow = qG + (size_t)(b * T_SEQ + qt * 64 + w * 16 + lr) * 1024 + (h << 6);
#pragma unroll
  for (int s = 0; s < 2; ++s) {
    const float4 a0 = *(const float4*)(qrow + s * 32 + lg * 8);
    const float4 a1 = *(const float4*)(qrow + s * 32 + lg * 8 + 4);
    const float xv[8] = {a0.x, a0.y, a0.z, a0.w, a1.x, a1.y, a1.z, a1.w};
#pragma unroll
    for (int j = 0; j < 8; ++j) {
      const float xs = xv[j] * 0.1803368801f;   // (1/8) * log2(e): exp2 domain
      const unsigned short hs = f2bf(xs);
      qh[s][j] = (short)hs;
      ql[s][j] = (short)f2bf(xs - bf2f(hs));
    }
  }
}

__device__ __forceinline__ void store_part(ushort_t* pO, float2* pml, TS2& st,
                                           int b, int qt, int h,
                                           int w, int lg, int lr) {
  float l = st.l;
  l += __shfl_xor(l, 16);
  l += __shfl_xor(l, 32);
  const int row = b * T_SEQ + qt * 64 + w * 16 + lr;
  ushort_t* orow = pO + (size_t)row * C_DIM + (h << 6) + (lg << 2);
#pragma unroll
  for (int n = 0; n < 4; ++n) {
    ushort4 o;
    o.x = f2bf(st.O[n][0]);
    o.y = f2bf(st.O[n][1]);
    o.z = f2bf(st.O[n][2]);
    o.w = f2bf(st.O[n][3]);
    *(ushort4*)(orow + 16 * n) = o;        // d = 16n + 4lg + r (unnormalized)
  }
  if (lg == 0)                              // m group-uniform; l reduced above
    pml[(size_t)row * NHEAD + h] = make_float2(st.m, l);
}

__global__ __launch_bounds__(256) void attn_sp_k(const float* __restrict__ qG,
                                                 const char* __restrict__ img,
                                                 ushort_t* __restrict__ pO0,
                                                 ushort_t* __restrict__ pO1,
                                                 float2* __restrict__ pml0,
                                                 float2* __restrict__ pml1) {
  __shared__ __align__(16) char smem[24576];   // single 64-key chunk image
  const int tid  = threadIdx.x;
  const int lane = tid & 63;
  const int w    = tid >> 6;
  const int lg   = lane >> 4;
  const int lr   = lane & 15;
  const int sh0  = lr + 32 * (lg & 1);     // P-gather source lanes
  const int sh1  = sh0 + 16;

  // gg low 5 bits (XCD-pinned img); parity adjacent; qt descending (LPT)
  const int bx = blockIdx.x;
  const int gg = bx & 31;
  const int s  = (bx >> 5) & 1;
  const int qt = 31 - (bx >> 6);
  const int h  = gg & 15, b = gg >> 4;

  ushort_t* const pO  = s ? pO1 : pO0;
  float2*   const pml = s ? pml1 : pml0;

  const char* img_gg = img + (size_t)gg * 32 * CHB;

  short8 qh[2], ql[2];
  load_q(qG, b, qt, h, w, lg, lr, qh, ql);

  TS2 st;
#pragma unroll
  for (int n = 0; n < 4; ++n) {
    const f32x4 z = {0.f, 0.f, 0.f, 0.f};
    st.O[n] = z;
  }
  st.m = -1e30f;
  st.l = 0.f;

  for (int c = s; c <= qt; c += 2) {
    __syncthreads();                         // prev compute done
    const char* src = img_gg + (size_t)c * CHB;
#pragma unroll
    for (int i = 0; i < 6; ++i)
      gll16(src + i * 4096 + tid * 16, smem + i * 4096 + tid * 16);
    __syncthreads();                         // vmcnt drained -> image ready

    const char* khp = smem;
    const char* klp = smem + 8192;
    const char* vTp = smem + 16384;

    // ---- swapped QK: S^T = mfma(K, Q) ----
    f32x4 s4[4];
    const f32x4 z = {0.f, 0.f, 0.f, 0.f};
#pragma unroll
    for (int f = 0; f < 4; ++f) s4[f] = z;
#pragma unroll
    for (int sx = 0; sx < 2; ++sx) {
      const int cb = sx * 64 + lg * 16;
#pragma unroll
      for (int f = 0; f < 4; ++f) {
        const int row = lr + 16 * f;
        const int byt = row * 128 + (cb ^ ((row & 7) << 4));
        const short8 kh8 = *(const short8*)(khp + byt);
        const short8 kl8 = *(const short8*)(klp + byt);
        s4[f] = __builtin_amdgcn_mfma_f32_16x16x32_bf16(kh8, qh[sx], s4[f], 0, 0, 0);
        s4[f] = __builtin_amdgcn_mfma_f32_16x16x32_bf16(kh8, ql[sx], s4[f], 0, 0, 0);
        s4[f] = __builtin_amdgcn_mfma_f32_16x16x32_bf16(kl8, qh[sx], s4[f], 0, 0, 0);
      }
    }
    post_qk(s4, st, vTp, c == qt, w, lg, lr, sh0, sh1);
  }

  store_part(pO, pml, st, b, qt, h, w, lg, lr);
}

// ---------------- merge the two split partials (exp2 domain) ----------------
__global__ __launch_bounds__(256) void merge_k(const ushort_t* __restrict__ pO0,
                                               const ushort_t* __restrict__ pO1,
                                               const float2* __restrict__ pml0,
                                               const float2* __restrict__ pml1,
                                               ushort_t* __restrict__ ah) {
  const int idx = blockIdx.x * 256 + threadIdx.x;    // 1M ushort4 items
  const int row = idx >> 8;
  const int c4  = idx & 255;
  const int h   = c4 >> 4;
  const float2 ml0 = pml0[(size_t)row * NHEAD + h];
  const float2 ml1 = pml1[(size_t)row * NHEAD + h];
  const float M  = fmaxf(ml0.x, ml1.x);
  const float w0 = exp2f(ml0.x - M);                 // 0 for empty split
  const float w1 = exp2f(ml1.x - M);
  const float inv = 1.f / (ml0.y * w0 + ml1.y * w1);
  const size_t o = (size_t)row * 256 + c4;
  const ushort4 a = ((const ushort4*)pO0)[o];
  const ushort4 bq = ((const ushort4*)pO1)[o];
  ushort4 r;
  r.x = f2bf((bf2f(a.x) * w0 + bf2f(bq.x) * w1) * inv);
  r.y = f2bf((bf2f(a.y) * w0 + bf2f(bq.y) * w1) * inv);
  r.z = f2bf((bf2f(a.z) * w0 + bf2f(bq.z) * w1) * inv);
  r.w = f2bf((bf2f(a.w) * w0 + bf2f(bq.w) * w1) * inv);
  ((ushort4*)ah)[o] = r;
}

// ---------------- launch ----------------------------------------------------
extern "C" void kernel_launch(void* const* d_in, const int* in_sizes, int n_in,
                              void* d_out, int out_size, void* d_ws, size_t ws_size,
                              hipStream_t stream) {
  const float* x      = (const float*)d_in[0];   // [4096][1024]
  const float* w_qkv  = (const float*)d_in[1];   // [3072][1024]
  const float* w_out  = (const float*)d_in[2];   // [1024][1024]
  float* out = (float*)d_out;                    // [4096][1024]

  // layout (no aliasing: gemm_qkv writes img while reading wt_qkv;
  // pO0 aliases xl which is dead after gemm_qkv)
  char* pch = (char*)d_ws;
  ushort_t* wt_out = (ushort_t*)pch;  pch += (size_t)C_DIM * C_DIM * 2;    // 2MB
  ushort_t* xh     = (ushort_t*)pch;  pch += (size_t)M_ROWS * C_DIM * 2;   // 8MB
  ushort_t* xl     = (ushort_t*)pch;  pch += (size_t)M_ROWS * C_DIM * 2;   // 8MB
  float*    qG     = (float*)pch;     pch += (size_t)M_ROWS * C_DIM * 4;   // 16MB
  ushort_t* wt_qkv = (ushort_t*)pch;  pch += (size_t)N_QKV * C_DIM * 2;    // 6.3MB
  char*     img    = pch;             pch += (size_t)32 * 32 * CHB;        // 25.2MB
  ushort_t* pO1    = (ushort_t*)pch;  pch += (size_t)M_ROWS * C_DIM * 2;   // 8MB
  float2*   pml0   = (float2*)pch;    pch += (size_t)M_ROWS * NHEAD * 8;   // 0.5MB
  float2*   pml1   = (float2*)pch;    pch += (size_t)M_ROWS * NHEAD * 8;   // 0.5MB
  float*    part   = (float*)pch;     pch += 512 * 4;
  float*    scales = (float*)pch;
  ushort_t* ah  = xh;   // x hi dead after gemm1 -> merged attn output
  ushort_t* pO0 = xl;   // x lo dead after gemm1 -> split-0 partial

  hipLaunchKernelGGL(abs2_k, dim3(384), dim3(256), 0, stream, w_qkv, w_out, part);
  hipLaunchKernelGGL(finalize2_k, dim3(2), dim3(256), 0, stream, part, scales);

  hipLaunchKernelGGL(prep_elem_k, dim3(20480), dim3(256), 0, stream,
                     w_qkv, w_out, x, wt_qkv, wt_out, xh, xl, scales);

  // fused qkv GEMM: Q -> qG fp32; K/V -> 64-key img chunks
  hipLaunchKernelGGL(gemm_qkv_k, dim3(N_QKV / 128, M_ROWS / 128), dim3(256), 0, stream,
                     xh, xl, wt_qkv, qG, img, C_DIM);

  // split-K attention partials (grid 2048, 24KB, LPT order)
  hipLaunchKernelGGL(attn_sp_k, dim3(2048), dim3(256), 0, stream,
                     qG, img, pO0, pO1, pml0, pml1);

  // merge partials -> ah (bf16)
  hipLaunchKernelGGL(merge_k, dim3(4096), dim3(256), 0, stream,
                     pO0, pO1, pml0, pml1, ah);

  // out = ah @ wt_out^T  (64x128 tiles -> 512 blocks, 2/CU)
  hipLaunchKernelGGL(gemm_out_k, dim3(C_DIM / 128, M_ROWS / 64), dim3(256), 0, stream,
                     ah, wt_out, out, C_DIM, C_DIM);
}

// Round 21
// 161.206 us; speedup vs baseline: 1.0332x; 1.0332x over previous
//
#include <hip/hip_runtime.h>
#include <math.h>

#define T_SEQ 2048
#define C_DIM 1024
#define NHEAD 16
#define HDIM 64
#define M_ROWS 4096   // B*T
#define N_QKV 3072    // 3*C
#define CHB 24576     // img bytes per 64-key chunk: khi 8K | klo 8K | vT 8K

typedef __attribute__((ext_vector_type(8))) short short8;   // 8 bf16 (4 VGPR)
typedef __attribute__((ext_vector_type(4))) float f32x4;    // MFMA C/D
typedef unsigned short ushort_t;

__device__ inline unsigned short f2bf(float x) {            // RNE f32->bf16
  union { float f; unsigned u; } v; v.f = x;
  unsigned r = v.u + 0x7FFF + ((v.u >> 16) & 1);
  return (unsigned short)(r >> 16);
}
__device__ inline float bf2f(unsigned short h) {
  union { unsigned u; float f; } v; v.u = ((unsigned)h) << 16; return v.f;
}
__device__ inline unsigned fbits(float x) {
  union { float f; unsigned u; } v; v.f = x; return v.u;
}

// async global->LDS, 16B per lane; LDS dest = wave-uniform base + lane*16
__device__ __forceinline__ void gll16(const char* g, char* l) {
  __builtin_amdgcn_global_load_lds(
      (const __attribute__((address_space(1))) unsigned*)g,
      (__attribute__((address_space(3))) unsigned*)l, 16, 0, 0);
}

// ---------------- fused abs-sum pass (both weights, one launch) -------------
__global__ __launch_bounds__(256) void abs2_k(const float* __restrict__ w_qkv,
                                              const float* __restrict__ w_out,
                                              float* __restrict__ part) {
  __shared__ float red[256];
  const int bx = blockIdx.x;
  const float* w;
  int n, nblk, bi;
  if (bx < 256) { w = w_qkv; n = N_QKV * C_DIM; nblk = 256; bi = bx; }
  else          { w = w_out; n = C_DIM * C_DIM; nblk = 128; bi = bx - 256; }
  float s = 0.f;
  for (int i = bi * 256 + threadIdx.x; i < n; i += nblk * 256)
    s += fabsf(w[i]);
  red[threadIdx.x] = s;
  __syncthreads();
  for (int st = 128; st > 0; st >>= 1) {
    if ((int)threadIdx.x < st) red[threadIdx.x] += red[threadIdx.x + st];
    __syncthreads();
  }
  if (threadIdx.x == 0) part[bx] = red[0];
}

__global__ __launch_bounds__(256) void finalize2_k(const float* __restrict__ part,
                                                   float* __restrict__ scales) {
  __shared__ float red[256];
  const int bx = blockIdx.x;
  const int lim = (bx == 0) ? 256 : 128;
  red[threadIdx.x] = ((int)threadIdx.x < lim) ? part[bx * 256 + threadIdx.x] : 0.f;
  __syncthreads();
  for (int st = 128; st > 0; st >>= 1) {
    if ((int)threadIdx.x < st) red[threadIdx.x] += red[threadIdx.x + st];
    __syncthreads();
  }
  if (threadIdx.x == 0) {
    float n = (bx == 0) ? (float)(N_QKV * C_DIM) : (float)(C_DIM * C_DIM);
    scales[bx] = fmaxf(red[0] / n, 1e-8f);
  }
}

// ---------------- fused elementwise, float4-vectorized ----------------------
// bx ranges (float4 indices): [0,3072) tern qkv; [3072,4096) tern out;
// [4096,8192) split x. All branches 4 elems/thread.
__global__ __launch_bounds__(256) void prep_elem_k(const float* __restrict__ w_qkv,
                                                   const float* __restrict__ w_out,
                                                   const float* __restrict__ x,
                                                   ushort_t* __restrict__ wt_qkv,
                                                   ushort_t* __restrict__ wt_out,
                                                   ushort_t* __restrict__ xh,
                                                   ushort_t* __restrict__ xl,
                                                   const float* __restrict__ scales) {
  const int bx = blockIdx.x;
  if (bx < 4096) {
    const float* w;
    ushort_t* wt;
    float s;
    int i;
    if (bx < 3072) { w = w_qkv; wt = wt_qkv; s = scales[0]; i = bx * 256 + threadIdx.x; }
    else           { w = w_out; wt = wt_out; s = scales[1]; i = (bx - 3072) * 256 + threadIdx.x; }
    const float4 v = ((const float4*)w)[i];
    const float vv[4] = {v.x, v.y, v.z, v.w};
    ushort_t tt[4];
#pragma unroll
    for (int j = 0; j < 4; ++j) {
      const float t = rintf(vv[j] / s);
      tt[j] = f2bf(fminf(1.f, fmaxf(-1.f, t)));
    }
    ((ushort4*)wt)[i] = make_ushort4(tt[0], tt[1], tt[2], tt[3]);
  } else {
    const int i = (bx - 4096) * 256 + threadIdx.x;      // float4 index
    const float4 v = ((const float4*)x)[i];
    const float vv[4] = {v.x, v.y, v.z, v.w};
    ushort_t hh[4], ll[4];
#pragma unroll
    for (int j = 0; j < 4; ++j) {
      hh[j] = f2bf(vv[j]);
      ll[j] = f2bf(vv[j] - bf2f(hh[j]));
    }
    ((ushort4*)xh)[i] = make_ushort4(hh[0], hh[1], hh[2], hh[3]);
    ((ushort4*)xl)[i] = make_ushort4(ll[0], ll[1], ll[2], ll[3]);
  }
}

// ---------------- fused qkv GEMM: hi/lo MFMA + direct img epilogue ----------
__global__ __launch_bounds__(256) void gemm_qkv_k(const ushort_t* __restrict__ Ah,
                                                  const ushort_t* __restrict__ Al,
                                                  const ushort_t* __restrict__ Bw,
                                                  float* __restrict__ qG,
                                                  char* __restrict__ img,
                                                  int Kd) {
  __shared__ __align__(16) char lds[49152];   // Ah 16K | Al 16K | B 16K
  const int tid = threadIdx.x;
  const int bm = blockIdx.y << 7, bn = blockIdx.x << 7;
  const int w = tid >> 6, lane = tid & 63;
  const int wm = (w >> 1) << 6, wn = (w & 1) << 6;
  const int fr = lane & 15, fc = lane >> 4;

  int srow[4], scol[4];
#pragma unroll
  for (int i = 0; i < 4; ++i) {
    const int slot = i * 256 + tid;
    const int r = slot >> 3, s = slot & 7;
    srow[i] = r;
    scol[i] = (s ^ (r & 7)) << 3;            // pre-swizzled source column
  }

  f32x4 acc[4][4];
  const f32x4 z = {0.f, 0.f, 0.f, 0.f};
#pragma unroll
  for (int i = 0; i < 4; ++i)
#pragma unroll
    for (int j = 0; j < 4; ++j) acc[i][j] = z;

  for (int k0 = 0; k0 < Kd; k0 += 64) {
    __syncthreads();
#pragma unroll
    for (int i = 0; i < 4; ++i) {
      const int d16 = (i * 256 + tid) * 16;
      const size_t ga = (size_t)(bm + srow[i]) * Kd + k0 + scol[i];
      const size_t gb = (size_t)(bn + srow[i]) * Kd + k0 + scol[i];
      gll16((const char*)(Ah + ga), lds + d16);
      gll16((const char*)(Al + ga), lds + 16384 + d16);
      gll16((const char*)(Bw + gb), lds + 32768 + d16);
    }
    __syncthreads();
#pragma unroll
    for (int ks = 0; ks < 2; ++ks) {
      short8 af[4], lf[4], bf[4];
#pragma unroll
      for (int i = 0; i < 4; ++i) {
        const int ra = wm + i * 16 + fr;
        const int ca = (ks * 64 + fc * 16) ^ ((ra & 7) << 4);
        af[i] = *(const short8*)(lds + ra * 128 + ca);
        lf[i] = *(const short8*)(lds + 16384 + ra * 128 + ca);
        const int rb = wn + i * 16 + fr;
        const int cbb = (ks * 64 + fc * 16) ^ ((rb & 7) << 4);
        bf[i] = *(const short8*)(lds + 32768 + rb * 128 + cbb);
      }
#pragma unroll
      for (int i = 0; i < 4; ++i)
#pragma unroll
        for (int j = 0; j < 4; ++j) {
          acc[i][j] = __builtin_amdgcn_mfma_f32_16x16x32_bf16(af[i], bf[j], acc[i][j], 0, 0, 0);
          acc[i][j] = __builtin_amdgcn_mfma_f32_16x16x32_bf16(lf[i], bf[j], acc[i][j], 0, 0, 0);
        }
    }
  }

  // ---- epilogue (block-uniform routing on bn) ----
  if (bn < 1024) {
    // Q: fp32 [4096][1024]
#pragma unroll
    for (int i = 0; i < 4; ++i)
#pragma unroll
      for (int j = 0; j < 4; ++j) {
        float* cp = qG + (size_t)(bm + wm + i * 16 + fc * 4) * 1024 + bn + wn + j * 16 + fr;
#pragma unroll
        for (int r = 0; r < 4; ++r) cp[(size_t)r * 1024] = acc[i][j][r];
      }
  } else if (bn < 2048) {
    // K -> img hi/lo: off = key*128 + ((d*2)^((key&7)<<4))
#pragma unroll
    for (int i = 0; i < 4; ++i) {
      const int row0 = bm + wm + i * 16 + fc * 4;
#pragma unroll
      for (int r = 0; r < 4; ++r) {
        const int row = row0 + r;
        const int bb = row >> 11, t = row & 2047;
        const int c = t >> 6, key = t & 63;
        const int ksw = (key & 7) << 4;
        char* const igb = img + ((size_t)(bb << 4) * 32) * CHB + (size_t)c * CHB + key * 128;
#pragma unroll
        for (int j = 0; j < 4; ++j) {
          const int col = bn + wn + j * 16 + fr - 1024;
          const int h = col >> 6, d = col & 63;
          char* const ig = igb + (size_t)(h * 32) * CHB;
          const float v = acc[i][j][r];
          const unsigned short hi = f2bf(v);
          const unsigned short lo = f2bf(v - bf2f(hi));
          const int off = (d * 2) ^ ksw;
          *(ushort_t*)(ig + off) = hi;
          *(ushort_t*)(ig + 8192 + off) = lo;
        }
      }
    }
  } else {
    // V -> img vT: off = 16384 + d*128 + ((key*2)^((d&7)<<4))
#pragma unroll
    for (int i = 0; i < 4; ++i) {
      const int row0 = bm + wm + i * 16 + fc * 4;
#pragma unroll
      for (int r = 0; r < 4; ++r) {
        const int row = row0 + r;
        const int bb = row >> 11, t = row & 2047;
        const int c = t >> 6, key = t & 63;
        char* const igb = img + ((size_t)(bb << 4) * 32) * CHB + (size_t)c * CHB + 16384;
#pragma unroll
        for (int j = 0; j < 4; ++j) {
          const int col = bn + wn + j * 16 + fr - 2048;
          const int h = col >> 6, d = col & 63;
          char* const ig = igb + (size_t)(h * 32) * CHB;
          const int off = d * 128 + ((key * 2) ^ ((d & 7) << 4));
          *(ushort_t*)(ig + off) = f2bf(acc[i][j][r]);
        }
      }
    }
  }
}

// ---------------- out projection GEMM: 64x128 tile, 2 blocks/CU -------------
__global__ __launch_bounds__(256) void gemm_out_k(const ushort_t* __restrict__ A,
                                                  const ushort_t* __restrict__ Bw,
                                                  float* __restrict__ C,
                                                  int Nd, int Kd) {
  __shared__ __align__(16) char lds[24576];   // A 8K | B 16K
  const int tid = threadIdx.x;
  const int bm = blockIdx.y << 6, bn = blockIdx.x << 7;
  const int w = tid >> 6, lane = tid & 63;
  const int wn = w << 5;                      // wave covers 32 N-cols
  const int fr = lane & 15, fc = lane >> 4;

  f32x4 acc[4][2];
  const f32x4 z = {0.f, 0.f, 0.f, 0.f};
#pragma unroll
  for (int i = 0; i < 4; ++i)
#pragma unroll
    for (int j = 0; j < 2; ++j) acc[i][j] = z;

  for (int k0 = 0; k0 < Kd; k0 += 64) {
    __syncthreads();
#pragma unroll
    for (int i = 0; i < 2; ++i) {            // A: 64 rows
      const int slot = i * 256 + tid;
      const int r = slot >> 3, s = slot & 7;
      gll16((const char*)(A + (size_t)(bm + r) * Kd + k0 + ((s ^ (r & 7)) << 3)),
            lds + slot * 16);
    }
#pragma unroll
    for (int i = 0; i < 4; ++i) {            // B: 128 rows
      const int slot = i * 256 + tid;
      const int r = slot >> 3, s = slot & 7;
      gll16((const char*)(Bw + (size_t)(bn + r) * Kd + k0 + ((s ^ (r & 7)) << 3)),
            lds + 8192 + slot * 16);
    }
    __syncthreads();
#pragma unroll
    for (int ks = 0; ks < 2; ++ks) {
      short8 af[4], bf[2];
#pragma unroll
      for (int i = 0; i < 4; ++i) {
        const int ra = i * 16 + fr;
        af[i] = *(const short8*)(lds + ra * 128 + ((ks * 64 + fc * 16) ^ ((ra & 7) << 4)));
      }
#pragma unroll
      for (int j = 0; j < 2; ++j) {
        const int rb = wn + j * 16 + fr;
        bf[j] = *(const short8*)(lds + 8192 + rb * 128 + ((ks * 64 + fc * 16) ^ ((rb & 7) << 4)));
      }
#pragma unroll
      for (int i = 0; i < 4; ++i)
#pragma unroll
        for (int j = 0; j < 2; ++j)
          acc[i][j] = __builtin_amdgcn_mfma_f32_16x16x32_bf16(af[i], bf[j], acc[i][j], 0, 0, 0);
    }
  }
#pragma unroll
  for (int i = 0; i < 4; ++i)
#pragma unroll
    for (int j = 0; j < 2; ++j) {
      float* cp = C + (size_t)(bm + i * 16 + fc * 4) * Nd + bn + wn + j * 16 + fr;
#pragma unroll
      for (int r = 0; r < 4; ++r) cp[(size_t)r * Nd] = acc[i][j][r];
    }
}

// ---------------- swapped-QK single-tile attention, dbuf 64-key chunks ------
struct TS2 { f32x4 O[4]; float m; float l; };

__device__ __forceinline__ void post_qk(f32x4* s4, TS2& st, const char* vTp,
                                        const bool diag, const int w, const int lg,
                                        const int lr, const int sh0, const int sh1) {
  if (diag) {
#pragma unroll
    for (int f = 0; f < 4; ++f)
#pragma unroll
      for (int r = 0; r < 4; ++r)
        if (16 * f + 4 * lg + r > w * 16 + lr) s4[f][r] = -1e30f;
  }
  float mc = fmaxf(fmaxf(s4[0][0], s4[0][1]), fmaxf(s4[0][2], s4[0][3]));
#pragma unroll
  for (int f = 1; f < 4; ++f)
#pragma unroll
    for (int r = 0; r < 4; ++r) mc = fmaxf(mc, s4[f][r]);
  if (__any(mc > st.m + 11.5f)) {          // defer-max (log2 units)
    mc = fmaxf(mc, __shfl_xor(mc, 16));
    mc = fmaxf(mc, __shfl_xor(mc, 32));
    const float mn = fmaxf(st.m, mc);
    const float rs = exp2f(st.m - mn);
    st.m = mn;
    st.l *= rs;
#pragma unroll
    for (int n = 0; n < 4; ++n)
#pragma unroll
      for (int r = 0; r < 4; ++r) st.O[n][r] *= rs;
  }
#pragma unroll
  for (int f = 0; f < 4; ++f)
#pragma unroll
    for (int r = 0; r < 4; ++r) s4[f][r] = exp2f(s4[f][r] - st.m);
#pragma unroll
  for (int f = 0; f < 4; ++f)
    st.l += (s4[f][0] + s4[f][1]) + (s4[f][2] + s4[f][3]);

  // pack adjacent key-pairs: D[f][rp] = bf16(p[2rp]) | bf16(p[2rp+1])<<16
  unsigned D[4][2];
#pragma unroll
  for (int f = 0; f < 4; ++f)
#pragma unroll
    for (int rp = 0; rp < 2; ++rp)
      D[f][rp] = (fbits(s4[f][2 * rp + 1]) & 0xFFFF0000u) | (fbits(s4[f][2 * rp]) >> 16);

  // gather group's P into B-operand order
  int g[4][2][2];
#pragma unroll
  for (int f = 0; f < 4; ++f)
#pragma unroll
    for (int rp = 0; rp < 2; ++rp) {
      g[f][rp][0] = __shfl((int)D[f][rp], sh0, 64);
      g[f][rp][1] = __shfl((int)D[f][rp], sh1, 64);
    }
  const bool hi2 = (lg & 2) != 0;
  union PB { int4 i; short8 s; } pb0, pb1;
  pb0.i.x = hi2 ? g[1][0][0] : g[0][0][0];
  pb0.i.y = hi2 ? g[1][1][0] : g[0][1][0];
  pb0.i.z = hi2 ? g[1][0][1] : g[0][0][1];
  pb0.i.w = hi2 ? g[1][1][1] : g[0][1][1];
  pb1.i.x = hi2 ? g[3][0][0] : g[2][0][0];
  pb1.i.y = hi2 ? g[3][1][0] : g[2][1][0];
  pb1.i.z = hi2 ? g[3][0][1] : g[2][0][1];
  pb1.i.w = hi2 ? g[3][1][1] : g[2][1][1];

  // PV: O^T[d][q] = mfma(A=V^T rows 16n+lr, B=P^T)
  const int swz = (lr & 7) << 4;
#pragma unroll
  for (int n = 0; n < 4; ++n) {
    const int d = 16 * n + lr;
    const short8 va0 = *(const short8*)(vTp + d * 128 + ((lg * 16) ^ swz));
    st.O[n] = __builtin_amdgcn_mfma_f32_16x16x32_bf16(va0, pb0.s, st.O[n], 0, 0, 0);
    const short8 va1 = *(const short8*)(vTp + d * 128 + ((64 + lg * 16) ^ swz));
    st.O[n] = __builtin_amdgcn_mfma_f32_16x16x32_bf16(va1, pb1.s, st.O[n], 0, 0, 0);
  }
}

__device__ __forceinline__ void load_q(const float* qG, int b, int qt, int h,
                                       int w, int lg, int lr,
                                       short8* qh, short8* ql) {
  const float* qrow = qG + (size_t)(b * T_SEQ + qt * 64 + w * 16 + lr) * 1024 + (h << 6);
#pragma unroll
  for (int s = 0; s < 2; ++s) {
    const float4 a0 = *(const float4*)(qrow + s * 32 + lg * 8);
    const float4 a1 = *(const float4*)(qrow + s * 32 + lg * 8 + 4);
    const float xv[8] = {a0.x, a0.y, a0.z, a0.w, a1.x, a1.y, a1.z, a1.w};
#pragma unroll
    for (int j = 0; j < 8; ++j) {
      const float xs = xv[j] * 0.1803368801f;   // (1/8) * log2(e): exp2 domain
      const unsigned short hs = f2bf(xs);
      qh[s][j] = (short)hs;
      ql[s][j] = (short)f2bf(xs - bf2f(hs));
    }
  }
}

__device__ __forceinline__ void store_o3(ushort_t* oh, TS2& st,
                                         int b, int qt, int h,
                                         int w, int lg, int lr) {
  float l = st.l;
  l += __shfl_xor(l, 16);
  l += __shfl_xor(l, 32);
  const float inv = 1.f / l;
  ushort_t* orow = oh + (size_t)(b * T_SEQ + qt * 64 + w * 16 + lr) * C_DIM
                   + (h << 6) + (lg << 2);
#pragma unroll
  for (int n = 0; n < 4; ++n) {
    ushort4 o;
    o.x = f2bf(st.O[n][0] * inv);
    o.y = f2bf(st.O[n][1] * inv);
    o.z = f2bf(st.O[n][2] * inv);
    o.w = f2bf(st.O[n][3] * inv);
    *(ushort4*)(orow + 16 * n) = o;        // d = 16n + 4lg + r
  }
}

__global__ __launch_bounds__(256) void attn1_k(const float* __restrict__ qG,
                                               const char* __restrict__ img,
                                               ushort_t* __restrict__ oh) {
  __shared__ __align__(16) char smem[49152];   // dbuf: 2 x 24KB chunk images
  const int tid  = threadIdx.x;
  const int lane = tid & 63;
  const int w    = tid >> 6;
  const int lg   = lane >> 4;
  const int lr   = lane & 15;
  const int sh0  = lr + 32 * (lg & 1);     // P-gather source lanes
  const int sh1  = sh0 + 16;

  // gg in low 5 bits (XCD-pinned img slice); qt descending (LPT balance)
  const int bx = blockIdx.x;
  const int gg = bx & 31;
  const int qt = 31 - (bx >> 5);
  const int h  = gg & 15, b = gg >> 4;

  const char* img_gg = img + (size_t)gg * 32 * CHB;

  short8 qh[2], ql[2];
  load_q(qG, b, qt, h, w, lg, lr, qh, ql);

  TS2 st;
#pragma unroll
  for (int n = 0; n < 4; ++n) {
    const f32x4 z = {0.f, 0.f, 0.f, 0.f};
    st.O[n] = z;
  }
  st.m = -1e30f;
  st.l = 0.f;

  // prologue: issue chunk 0 into buf0
#pragma unroll
  for (int i = 0; i < 6; ++i)
    gll16(img_gg + i * 4096 + tid * 16, smem + i * 4096 + tid * 16);

  int cur = 0;
  for (int c = 0; c <= qt; ++c) {
    __syncthreads();                         // drains loads -> buf[cur] ready
    if (c < qt) {
      const char* src = img_gg + (size_t)(c + 1) * CHB;
      char* dst = smem + (cur ^ 1) * CHB;
#pragma unroll
      for (int i = 0; i < 6; ++i)
        gll16(src + i * 4096 + tid * 16, dst + i * 4096 + tid * 16);
    }
    const char* khp = smem + cur * CHB;
    const char* klp = khp + 8192;
    const char* vTp = khp + 16384;

    // ---- swapped QK: S^T = mfma(K, Q) ----
    f32x4 s4[4];
    const f32x4 z = {0.f, 0.f, 0.f, 0.f};
#pragma unroll
    for (int f = 0; f < 4; ++f) s4[f] = z;
#pragma unroll
    for (int s = 0; s < 2; ++s) {
      const int cb = s * 64 + lg * 16;
#pragma unroll
      for (int f = 0; f < 4; ++f) {
        const int row = lr + 16 * f;
        const int byt = row * 128 + (cb ^ ((row & 7) << 4));
        const short8 kh8 = *(const short8*)(khp + byt);
        const short8 kl8 = *(const short8*)(klp + byt);
        s4[f] = __builtin_amdgcn_mfma_f32_16x16x32_bf16(kh8, qh[s], s4[f], 0, 0, 0);
        s4[f] = __builtin_amdgcn_mfma_f32_16x16x32_bf16(kh8, ql[s], s4[f], 0, 0, 0);
        s4[f] = __builtin_amdgcn_mfma_f32_16x16x32_bf16(kl8, qh[s], s4[f], 0, 0, 0);
      }
    }
    post_qk(s4, st, vTp, c == qt, w, lg, lr, sh0, sh1);

    cur ^= 1;
  }

  store_o3(oh, st, b, qt, h, w, lg, lr);
}

// ---------------- launch ----------------------------------------------------
extern "C" void kernel_launch(void* const* d_in, const int* in_sizes, int n_in,
                              void* d_out, int out_size, void* d_ws, size_t ws_size,
                              hipStream_t stream) {
  const float* x      = (const float*)d_in[0];   // [4096][1024]
  const float* w_qkv  = (const float*)d_in[1];   // [3072][1024]
  const float* w_out  = (const float*)d_in[2];   // [1024][1024]
  float* out = (float*)d_out;                    // [4096][1024]

  // layout (no aliasing: gemm_qkv writes img while reading wt_qkv)
  char* pch = (char*)d_ws;
  ushort_t* wt_out = (ushort_t*)pch;  pch += (size_t)C_DIM * C_DIM * 2;    // 2MB
  ushort_t* xh     = (ushort_t*)pch;  pch += (size_t)M_ROWS * C_DIM * 2;   // 8MB
  ushort_t* xl     = (ushort_t*)pch;  pch += (size_t)M_ROWS * C_DIM * 2;   // 8MB
  float*    qG     = (float*)pch;     pch += (size_t)M_ROWS * C_DIM * 4;   // 16MB
  ushort_t* wt_qkv = (ushort_t*)pch;  pch += (size_t)N_QKV * C_DIM * 2;    // 6.3MB
  char*     img    = pch;             pch += (size_t)32 * 32 * CHB;        // 25.2MB
  float*    part   = (float*)pch;     pch += 512 * 4;
  float*    scales = (float*)pch;
  ushort_t* ah = xh;   // x hi dead after gemm1 -> attn output

  hipLaunchKernelGGL(abs2_k, dim3(384), dim3(256), 0, stream, w_qkv, w_out, part);
  hipLaunchKernelGGL(finalize2_k, dim3(2), dim3(256), 0, stream, part, scales);

  hipLaunchKernelGGL(prep_elem_k, dim3(8192), dim3(256), 0, stream,
                     w_qkv, w_out, x, wt_qkv, wt_out, xh, xl, scales);

  // fused qkv GEMM: Q -> qG fp32; K/V -> 64-key img chunks
  hipLaunchKernelGGL(gemm_qkv_k, dim3(N_QKV / 128, M_ROWS / 128), dim3(256), 0, stream,
                     xh, xl, wt_qkv, qG, img, C_DIM);

  // attention -> bf16 (single-tile, dbuf 48KB, LPT order)
  hipLaunchKernelGGL(attn1_k, dim3(1024), dim3(256), 0, stream, qG, img, ah);

  // out = ah @ wt_out^T  (64x128 tiles -> 512 blocks, 2/CU)
  hipLaunchKernelGGL(gemm_out_k, dim3(C_DIM / 128, M_ROWS / 64), dim3(256), 0, stream,
                     ah, wt_out, out, C_DIM, C_DIM);
}

// Round 22
// 159.691 us; speedup vs baseline: 1.0430x; 1.0095x over previous
//
#include <hip/hip_runtime.h>
#include <math.h>

#define T_SEQ 2048
#define C_DIM 1024
#define NHEAD 16
#define HDIM 64
#define M_ROWS 4096   // B*T
#define N_QKV 3072    // 3*C
#define CHB 24576     // img bytes per 64-key chunk: khi 8K | klo 8K | vT 8K

typedef __attribute__((ext_vector_type(8))) short short8;   // 8 bf16 (4 VGPR)
typedef __attribute__((ext_vector_type(4))) float f32x4;    // MFMA C/D
typedef unsigned short ushort_t;

__device__ inline unsigned short f2bf(float x) {            // RNE f32->bf16
  union { float f; unsigned u; } v; v.f = x;
  unsigned r = v.u + 0x7FFF + ((v.u >> 16) & 1);
  return (unsigned short)(r >> 16);
}
__device__ inline float bf2f(unsigned short h) {
  union { unsigned u; float f; } v; v.u = ((unsigned)h) << 16; return v.f;
}
__device__ inline unsigned fbits(float x) {
  union { float f; unsigned u; } v; v.f = x; return v.u;
}

// async global->LDS, 16B per lane; LDS dest = wave-uniform base + lane*16
__device__ __forceinline__ void gll16(const char* g, char* l) {
  __builtin_amdgcn_global_load_lds(
      (const __attribute__((address_space(1))) unsigned*)g,
      (__attribute__((address_space(3))) unsigned*)l, 16, 0, 0);
}

// ---------------- fused abs-sum pass (both weights, one launch) -------------
__global__ __launch_bounds__(256) void abs2_k(const float* __restrict__ w_qkv,
                                              const float* __restrict__ w_out,
                                              float* __restrict__ part) {
  __shared__ float red[256];
  const int bx = blockIdx.x;
  const float* w;
  int n, nblk, bi;
  if (bx < 256) { w = w_qkv; n = N_QKV * C_DIM; nblk = 256; bi = bx; }
  else          { w = w_out; n = C_DIM * C_DIM; nblk = 128; bi = bx - 256; }
  float s = 0.f;
  for (int i = bi * 256 + threadIdx.x; i < n; i += nblk * 256)
    s += fabsf(w[i]);
  red[threadIdx.x] = s;
  __syncthreads();
  for (int st = 128; st > 0; st >>= 1) {
    if ((int)threadIdx.x < st) red[threadIdx.x] += red[threadIdx.x + st];
    __syncthreads();
  }
  if (threadIdx.x == 0) part[bx] = red[0];
}

__global__ __launch_bounds__(256) void finalize2_k(const float* __restrict__ part,
                                                   float* __restrict__ scales) {
  __shared__ float red[256];
  const int bx = blockIdx.x;
  const int lim = (bx == 0) ? 256 : 128;
  red[threadIdx.x] = ((int)threadIdx.x < lim) ? part[bx * 256 + threadIdx.x] : 0.f;
  __syncthreads();
  for (int st = 128; st > 0; st >>= 1) {
    if ((int)threadIdx.x < st) red[threadIdx.x] += red[threadIdx.x + st];
    __syncthreads();
  }
  if (threadIdx.x == 0) {
    float n = (bx == 0) ? (float)(N_QKV * C_DIM) : (float)(C_DIM * C_DIM);
    scales[bx] = fmaxf(red[0] / n, 1e-8f);
  }
}

// ---------------- fused elementwise, float4-vectorized ----------------------
__global__ __launch_bounds__(256) void prep_elem_k(const float* __restrict__ w_qkv,
                                                   const float* __restrict__ w_out,
                                                   const float* __restrict__ x,
                                                   ushort_t* __restrict__ wt_qkv,
                                                   ushort_t* __restrict__ wt_out,
                                                   ushort_t* __restrict__ xh,
                                                   ushort_t* __restrict__ xl,
                                                   const float* __restrict__ scales) {
  const int bx = blockIdx.x;
  if (bx < 4096) {
    const float* w;
    ushort_t* wt;
    float s;
    int i;
    if (bx < 3072) { w = w_qkv; wt = wt_qkv; s = scales[0]; i = bx * 256 + threadIdx.x; }
    else           { w = w_out; wt = wt_out; s = scales[1]; i = (bx - 3072) * 256 + threadIdx.x; }
    const float4 v = ((const float4*)w)[i];
    const float vv[4] = {v.x, v.y, v.z, v.w};
    ushort_t tt[4];
#pragma unroll
    for (int j = 0; j < 4; ++j) {
      const float t = rintf(vv[j] / s);
      tt[j] = f2bf(fminf(1.f, fmaxf(-1.f, t)));
    }
    ((ushort4*)wt)[i] = make_ushort4(tt[0], tt[1], tt[2], tt[3]);
  } else {
    const int i = (bx - 4096) * 256 + threadIdx.x;      // float4 index
    const float4 v = ((const float4*)x)[i];
    const float vv[4] = {v.x, v.y, v.z, v.w};
    ushort_t hh[4], ll[4];
#pragma unroll
    for (int j = 0; j < 4; ++j) {
      hh[j] = f2bf(vv[j]);
      ll[j] = f2bf(vv[j] - bf2f(hh[j]));
    }
    ((ushort4*)xh)[i] = make_ushort4(hh[0], hh[1], hh[2], hh[3]);
    ((ushort4*)xl)[i] = make_ushort4(ll[0], ll[1], ll[2], ll[3]);
  }
}

// ---------------- fused qkv GEMM: hi/lo MFMA + direct img epilogue ----------
// V epilogue now bounces through a wave-private padded LDS slice so the
// global write is 8KB contiguous per wave (was 16x 128B-strided 2B scatters).
__global__ __launch_bounds__(256) void gemm_qkv_k(const ushort_t* __restrict__ Ah,
                                                  const ushort_t* __restrict__ Al,
                                                  const ushort_t* __restrict__ Bw,
                                                  float* __restrict__ qG,
                                                  char* __restrict__ img,
                                                  int Kd) {
  __shared__ __align__(16) char lds[49152];   // Ah 16K | Al 16K | B 16K
  const int tid = threadIdx.x;
  const int bm = blockIdx.y << 7, bn = blockIdx.x << 7;
  const int w = tid >> 6, lane = tid & 63;
  const int wm = (w >> 1) << 6, wn = (w & 1) << 6;
  const int fr = lane & 15, fc = lane >> 4;

  int srow[4], scol[4];
#pragma unroll
  for (int i = 0; i < 4; ++i) {
    const int slot = i * 256 + tid;
    const int r = slot >> 3, s = slot & 7;
    srow[i] = r;
    scol[i] = (s ^ (r & 7)) << 3;            // pre-swizzled source column
  }

  f32x4 acc[4][4];
  const f32x4 z = {0.f, 0.f, 0.f, 0.f};
#pragma unroll
  for (int i = 0; i < 4; ++i)
#pragma unroll
    for (int j = 0; j < 4; ++j) acc[i][j] = z;

  for (int k0 = 0; k0 < Kd; k0 += 64) {
    __syncthreads();
#pragma unroll
    for (int i = 0; i < 4; ++i) {
      const int d16 = (i * 256 + tid) * 16;
      const size_t ga = (size_t)(bm + srow[i]) * Kd + k0 + scol[i];
      const size_t gb = (size_t)(bn + srow[i]) * Kd + k0 + scol[i];
      gll16((const char*)(Ah + ga), lds + d16);
      gll16((const char*)(Al + ga), lds + 16384 + d16);
      gll16((const char*)(Bw + gb), lds + 32768 + d16);
    }
    __syncthreads();
#pragma unroll
    for (int ks = 0; ks < 2; ++ks) {
      short8 af[4], lf[4], bf[4];
#pragma unroll
      for (int i = 0; i < 4; ++i) {
        const int ra = wm + i * 16 + fr;
        const int ca = (ks * 64 + fc * 16) ^ ((ra & 7) << 4);
        af[i] = *(const short8*)(lds + ra * 128 + ca);
        lf[i] = *(const short8*)(lds + 16384 + ra * 128 + ca);
        const int rb = wn + i * 16 + fr;
        const int cbb = (ks * 64 + fc * 16) ^ ((rb & 7) << 4);
        bf[i] = *(const short8*)(lds + 32768 + rb * 128 + cbb);
      }
#pragma unroll
      for (int i = 0; i < 4; ++i)
#pragma unroll
        for (int j = 0; j < 4; ++j) {
          acc[i][j] = __builtin_amdgcn_mfma_f32_16x16x32_bf16(af[i], bf[j], acc[i][j], 0, 0, 0);
          acc[i][j] = __builtin_amdgcn_mfma_f32_16x16x32_bf16(lf[i], bf[j], acc[i][j], 0, 0, 0);
        }
    }
  }

  // ---- epilogue (block-uniform routing on bn) ----
  if (bn < 1024) {
    // Q: fp32 [4096][1024]
#pragma unroll
    for (int i = 0; i < 4; ++i)
#pragma unroll
      for (int j = 0; j < 4; ++j) {
        float* cp = qG + (size_t)(bm + wm + i * 16 + fc * 4) * 1024 + bn + wn + j * 16 + fr;
#pragma unroll
        for (int r = 0; r < 4; ++r) cp[(size_t)r * 1024] = acc[i][j][r];
      }
  } else if (bn < 2048) {
    // K -> img hi/lo: off = key*128 + ((d*2)^((key&7)<<4))  (16-lane 32B segs)
#pragma unroll
    for (int i = 0; i < 4; ++i) {
      const int row0 = bm + wm + i * 16 + fc * 4;
#pragma unroll
      for (int r = 0; r < 4; ++r) {
        const int row = row0 + r;
        const int bb = row >> 11, t = row & 2047;
        const int c = t >> 6, key = t & 63;
        const int ksw = (key & 7) << 4;
        char* const igb = img + ((size_t)(bb << 4) * 32) * CHB + (size_t)c * CHB + key * 128;
#pragma unroll
        for (int j = 0; j < 4; ++j) {
          const int col = bn + wn + j * 16 + fr - 1024;
          const int h = col >> 6, d = col & 63;
          char* const ig = igb + (size_t)(h * 32) * CHB;
          const float v = acc[i][j][r];
          const unsigned short hi = f2bf(v);
          const unsigned short lo = f2bf(v - bf2f(hi));
          const int off = (d * 2) ^ ksw;
          *(ushort_t*)(ig + off) = hi;
          *(ushort_t*)(ig + 8192 + off) = lo;
        }
      }
    }
  } else {
    // V: wave's acc quarter == one (chunk,head) vT slice (64d x 64key, 8KB).
    // Stage into wave-private padded LDS (144B row stride), then copy out
    // 8KB contiguous (8 x int4 per lane, fully coalesced).
    __syncthreads();                          // K-loop LDS now dead for ALL waves
    char* const vst = lds + w * 9216;         // 64 rows x 144B
#pragma unroll
    for (int i = 0; i < 4; ++i)
#pragma unroll
      for (int r = 0; r < 4; ++r) {
        const int key = i * 16 + fc * 4 + r;  // key within slice
#pragma unroll
        for (int j = 0; j < 4; ++j) {
          const int d = j * 16 + fr;          // d within slice
          const int off = d * 144 + ((key * 2) ^ ((d & 7) << 4));
          *(ushort_t*)(vst + off) = f2bf(acc[i][j][r]);
        }
      }
    // slice destination (row/col uniform per wave)
    const int row0 = bm + wm;
    const int bb = row0 >> 11, c = (row0 & 2047) >> 6;
    const int h = (bn + wn - 2048) >> 6;
    char* const dst = img + ((size_t)(bb << 4) * 32) * CHB + (size_t)c * CHB
                      + ((size_t)(h * 32)) * CHB + 16384;
#pragma unroll
    for (int t = 0; t < 8; ++t) {
      const int o = t * 1024 + lane * 16;     // byte offset in 8KB slice
      const int4 v = *(const int4*)(vst + (o >> 7) * 144 + (o & 127));
      *(int4*)(dst + o) = v;
    }
  }
}

// ---------------- out projection GEMM: 64x128 tile, 2 blocks/CU -------------
__global__ __launch_bounds__(256) void gemm_out_k(const ushort_t* __restrict__ A,
                                                  const ushort_t* __restrict__ Bw,
                                                  float* __restrict__ C,
                                                  int Nd, int Kd) {
  __shared__ __align__(16) char lds[24576];   // A 8K | B 16K
  const int tid = threadIdx.x;
  const int bm = blockIdx.y << 6, bn = blockIdx.x << 7;
  const int w = tid >> 6, lane = tid & 63;
  const int wn = w << 5;                      // wave covers 32 N-cols
  const int fr = lane & 15, fc = lane >> 4;

  f32x4 acc[4][2];
  const f32x4 z = {0.f, 0.f, 0.f, 0.f};
#pragma unroll
  for (int i = 0; i < 4; ++i)
#pragma unroll
    for (int j = 0; j < 2; ++j) acc[i][j] = z;

  for (int k0 = 0; k0 < Kd; k0 += 64) {
    __syncthreads();
#pragma unroll
    for (int i = 0; i < 2; ++i) {            // A: 64 rows
      const int slot = i * 256 + tid;
      const int r = slot >> 3, s = slot & 7;
      gll16((const char*)(A + (size_t)(bm + r) * Kd + k0 + ((s ^ (r & 7)) << 3)),
            lds + slot * 16);
    }
#pragma unroll
    for (int i = 0; i < 4; ++i) {            // B: 128 rows
      const int slot = i * 256 + tid;
      const int r = slot >> 3, s = slot & 7;
      gll16((const char*)(Bw + (size_t)(bn + r) * Kd + k0 + ((s ^ (r & 7)) << 3)),
            lds + 8192 + slot * 16);
    }
    __syncthreads();
#pragma unroll
    for (int ks = 0; ks < 2; ++ks) {
      short8 af[4], bf[2];
#pragma unroll
      for (int i = 0; i < 4; ++i) {
        const int ra = i * 16 + fr;
        af[i] = *(const short8*)(lds + ra * 128 + ((ks * 64 + fc * 16) ^ ((ra & 7) << 4)));
      }
#pragma unroll
      for (int j = 0; j < 2; ++j) {
        const int rb = wn + j * 16 + fr;
        bf[j] = *(const short8*)(lds + 8192 + rb * 128 + ((ks * 64 + fc * 16) ^ ((rb & 7) << 4)));
      }
#pragma unroll
      for (int i = 0; i < 4; ++i)
#pragma unroll
        for (int j = 0; j < 2; ++j)
          acc[i][j] = __builtin_amdgcn_mfma_f32_16x16x32_bf16(af[i], bf[j], acc[i][j], 0, 0, 0);
    }
  }
#pragma unroll
  for (int i = 0; i < 4; ++i)
#pragma unroll
    for (int j = 0; j < 2; ++j) {
      float* cp = C + (size_t)(bm + i * 16 + fc * 4) * Nd + bn + wn + j * 16 + fr;
#pragma unroll
      for (int r = 0; r < 4; ++r) cp[(size_t)r * Nd] = acc[i][j][r];
    }
}

// ---------------- swapped-QK single-tile attention, dbuf 64-key chunks ------
struct TS2 { f32x4 O[4]; float m; float l; };

__device__ __forceinline__ void post_qk(f32x4* s4, TS2& st, const char* vTp,
                                        const bool diag, const int w, const int lg,
                                        const int lr, const int sh0, const int sh1) {
  if (diag) {
#pragma unroll
    for (int f = 0; f < 4; ++f)
#pragma unroll
      for (int r = 0; r < 4; ++r)
        if (16 * f + 4 * lg + r > w * 16 + lr) s4[f][r] = -1e30f;
  }
  float mc = fmaxf(fmaxf(s4[0][0], s4[0][1]), fmaxf(s4[0][2], s4[0][3]));
#pragma unroll
  for (int f = 1; f < 4; ++f)
#pragma unroll
    for (int r = 0; r < 4; ++r) mc = fmaxf(mc, s4[f][r]);
  if (__any(mc > st.m + 11.5f)) {          // defer-max (log2 units)
    mc = fmaxf(mc, __shfl_xor(mc, 16));
    mc = fmaxf(mc, __shfl_xor(mc, 32));
    const float mn = fmaxf(st.m, mc);
    const float rs = exp2f(st.m - mn);
    st.m = mn;
    st.l *= rs;
#pragma unroll
    for (int n = 0; n < 4; ++n)
#pragma unroll
      for (int r = 0; r < 4; ++r) st.O[n][r] *= rs;
  }
#pragma unroll
  for (int f = 0; f < 4; ++f)
#pragma unroll
    for (int r = 0; r < 4; ++r) s4[f][r] = exp2f(s4[f][r] - st.m);
#pragma unroll
  for (int f = 0; f < 4; ++f)
    st.l += (s4[f][0] + s4[f][1]) + (s4[f][2] + s4[f][3]);

  // pack adjacent key-pairs: D[f][rp] = bf16(p[2rp]) | bf16(p[2rp+1])<<16
  unsigned D[4][2];
#pragma unroll
  for (int f = 0; f < 4; ++f)
#pragma unroll
    for (int rp = 0; rp < 2; ++rp)
      D[f][rp] = (fbits(s4[f][2 * rp + 1]) & 0xFFFF0000u) | (fbits(s4[f][2 * rp]) >> 16);

  // gather group's P into B-operand order
  int g[4][2][2];
#pragma unroll
  for (int f = 0; f < 4; ++f)
#pragma unroll
    for (int rp = 0; rp < 2; ++rp) {
      g[f][rp][0] = __shfl((int)D[f][rp], sh0, 64);
      g[f][rp][1] = __shfl((int)D[f][rp], sh1, 64);
    }
  const bool hi2 = (lg & 2) != 0;
  union PB { int4 i; short8 s; } pb0, pb1;
  pb0.i.x = hi2 ? g[1][0][0] : g[0][0][0];
  pb0.i.y = hi2 ? g[1][1][0] : g[0][1][0];
  pb0.i.z = hi2 ? g[1][0][1] : g[0][0][1];
  pb0.i.w = hi2 ? g[1][1][1] : g[0][1][1];
  pb1.i.x = hi2 ? g[3][0][0] : g[2][0][0];
  pb1.i.y = hi2 ? g[3][1][0] : g[2][1][0];
  pb1.i.z = hi2 ? g[3][0][1] : g[2][0][1];
  pb1.i.w = hi2 ? g[3][1][1] : g[2][1][1];

  // PV: O^T[d][q] = mfma(A=V^T rows 16n+lr, B=P^T)
  const int swz = (lr & 7) << 4;
#pragma unroll
  for (int n = 0; n < 4; ++n) {
    const int d = 16 * n + lr;
    const short8 va0 = *(const short8*)(vTp + d * 128 + ((lg * 16) ^ swz));
    st.O[n] = __builtin_amdgcn_mfma_f32_16x16x32_bf16(va0, pb0.s, st.O[n], 0, 0, 0);
    const short8 va1 = *(const short8*)(vTp + d * 128 + ((64 + lg * 16) ^ swz));
    st.O[n] = __builtin_amdgcn_mfma_f32_16x16x32_bf16(va1, pb1.s, st.O[n], 0, 0, 0);
  }
}

__device__ __forceinline__ void load_q(const float* qG, int b, int qt, int h,
                                       int w, int lg, int lr,
                                       short8* qh, short8* ql) {
  const float* qrow = qG + (size_t)(b * T_SEQ + qt * 64 + w * 16 + lr) * 1024 + (h << 6);
#pragma unroll
  for (int s = 0; s < 2; ++s) {
    const float4 a0 = *(const float4*)(qrow + s * 32 + lg * 8);
    const float4 a1 = *(const float4*)(qrow + s * 32 + lg * 8 + 4);
    const float xv[8] = {a0.x, a0.y, a0.z, a0.w, a1.x, a1.y, a1.z, a1.w};
#pragma unroll
    for (int j = 0; j < 8; ++j) {
      const float xs = xv[j] * 0.1803368801f;   // (1/8) * log2(e): exp2 domain
      const unsigned short hs = f2bf(xs);
      qh[s][j] = (short)hs;
      ql[s][j] = (short)f2bf(xs - bf2f(hs));
    }
  }
}

__device__ __forceinline__ void store_o3(ushort_t* oh, TS2& st,
                                         int b, int qt, int h,
                                         int w, int lg, int lr) {
  float l = st.l;
  l += __shfl_xor(l, 16);
  l += __shfl_xor(l, 32);
  const float inv = 1.f / l;
  ushort_t* orow = oh + (size_t)(b * T_SEQ + qt * 64 + w * 16 + lr) * C_DIM
                   + (h << 6) + (lg << 2);
#pragma unroll
  for (int n = 0; n < 4; ++n) {
    ushort4 o;
    o.x = f2bf(st.O[n][0] * inv);
    o.y = f2bf(st.O[n][1] * inv);
    o.z = f2bf(st.O[n][2] * inv);
    o.w = f2bf(st.O[n][3] * inv);
    *(ushort4*)(orow + 16 * n) = o;        // d = 16n + 4lg + r
  }
}

__global__ __launch_bounds__(256) void attn1_k(const float* __restrict__ qG,
                                               const char* __restrict__ img,
                                               ushort_t* __restrict__ oh) {
  __shared__ __align__(16) char smem[49152];   // dbuf: 2 x 24KB chunk images
  const int tid  = threadIdx.x;
  const int lane = tid & 63;
  const int w    = tid >> 6;
  const int lg   = lane >> 4;
  const int lr   = lane & 15;
  const int sh0  = lr + 32 * (lg & 1);     // P-gather source lanes
  const int sh1  = sh0 + 16;

  // gg in low 5 bits (XCD-pinned img slice); qt descending (LPT balance)
  const int bx = blockIdx.x;
  const int gg = bx & 31;
  const int qt = 31 - (bx >> 5);
  const int h  = gg & 15, b = gg >> 4;

  const char* img_gg = img + (size_t)gg * 32 * CHB;

  short8 qh[2], ql[2];
  load_q(qG, b, qt, h, w, lg, lr, qh, ql);

  TS2 st;
#pragma unroll
  for (int n = 0; n < 4; ++n) {
    const f32x4 z = {0.f, 0.f, 0.f, 0.f};
    st.O[n] = z;
  }
  st.m = -1e30f;
  st.l = 0.f;

  // prologue: issue chunk 0 into buf0
#pragma unroll
  for (int i = 0; i < 6; ++i)
    gll16(img_gg + i * 4096 + tid * 16, smem + i * 4096 + tid * 16);

  int cur = 0;
  for (int c = 0; c <= qt; ++c) {
    __syncthreads();                         // drains loads -> buf[cur] ready
    if (c < qt) {
      const char* src = img_gg + (size_t)(c + 1) * CHB;
      char* dst = smem + (cur ^ 1) * CHB;
#pragma unroll
      for (int i = 0; i < 6; ++i)
        gll16(src + i * 4096 + tid * 16, dst + i * 4096 + tid * 16);
    }
    const char* khp = smem + cur * CHB;
    const char* klp = khp + 8192;
    const char* vTp = khp + 16384;

    // ---- swapped QK: S^T = mfma(K, Q) ----
    f32x4 s4[4];
    const f32x4 z = {0.f, 0.f, 0.f, 0.f};
#pragma unroll
    for (int f = 0; f < 4; ++f) s4[f] = z;
#pragma unroll
    for (int s = 0; s < 2; ++s) {
      const int cb = s * 64 + lg * 16;
#pragma unroll
      for (int f = 0; f < 4; ++f) {
        const int row = lr + 16 * f;
        const int byt = row * 128 + (cb ^ ((row & 7) << 4));
        const short8 kh8 = *(const short8*)(khp + byt);
        const short8 kl8 = *(const short8*)(klp + byt);
        s4[f] = __builtin_amdgcn_mfma_f32_16x16x32_bf16(kh8, qh[s], s4[f], 0, 0, 0);
        s4[f] = __builtin_amdgcn_mfma_f32_16x16x32_bf16(kh8, ql[s], s4[f], 0, 0, 0);
        s4[f] = __builtin_amdgcn_mfma_f32_16x16x32_bf16(kl8, qh[s], s4[f], 0, 0, 0);
      }
    }
    post_qk(s4, st, vTp, c == qt, w, lg, lr, sh0, sh1);

    cur ^= 1;
  }

  store_o3(oh, st, b, qt, h, w, lg, lr);
}

// ---------------- launch ----------------------------------------------------
extern "C" void kernel_launch(void* const* d_in, const int* in_sizes, int n_in,
                              void* d_out, int out_size, void* d_ws, size_t ws_size,
                              hipStream_t stream) {
  const float* x      = (const float*)d_in[0];   // [4096][1024]
  const float* w_qkv  = (const float*)d_in[1];   // [3072][1024]
  const float* w_out  = (const float*)d_in[2];   // [1024][1024]
  float* out = (float*)d_out;                    // [4096][1024]

  // layout (no aliasing: gemm_qkv writes img while reading wt_qkv)
  char* pch = (char*)d_ws;
  ushort_t* wt_out = (ushort_t*)pch;  pch += (size_t)C_DIM * C_DIM * 2;    // 2MB
  ushort_t* xh     = (ushort_t*)pch;  pch += (size_t)M_ROWS * C_DIM * 2;   // 8MB
  ushort_t* xl     = (ushort_t*)pch;  pch += (size_t)M_ROWS * C_DIM * 2;   // 8MB
  float*    qG     = (float*)pch;     pch += (size_t)M_ROWS * C_DIM * 4;   // 16MB
  ushort_t* wt_qkv = (ushort_t*)pch;  pch += (size_t)N_QKV * C_DIM * 2;    // 6.3MB
  char*     img    = pch;             pch += (size_t)32 * 32 * CHB;        // 25.2MB
  float*    part   = (float*)pch;     pch += 512 * 4;
  float*    scales = (float*)pch;
  ushort_t* ah = xh;   // x hi dead after gemm1 -> attn output

  hipLaunchKernelGGL(abs2_k, dim3(384), dim3(256), 0, stream, w_qkv, w_out, part);
  hipLaunchKernelGGL(finalize2_k, dim3(2), dim3(256), 0, stream, part, scales);

  hipLaunchKernelGGL(prep_elem_k, dim3(8192), dim3(256), 0, stream,
                     w_qkv, w_out, x, wt_qkv, wt_out, xh, xl, scales);

  // fused qkv GEMM: Q -> qG fp32; K/V -> 64-key img chunks
  hipLaunchKernelGGL(gemm_qkv_k, dim3(N_QKV / 128, M_ROWS / 128), dim3(256), 0, stream,
                     xh, xl, wt_qkv, qG, img, C_DIM);

  // attention -> bf16 (single-tile, dbuf 48KB, LPT order)
  hipLaunchKernelGGL(attn1_k, dim3(1024), dim3(256), 0, stream, qG, img, ah);

  // out = ah @ wt_out^T  (64x128 tiles -> 512 blocks, 2/CU)
  hipLaunchKernelGGL(gemm_out_k, dim3(C_DIM / 128, M_ROWS / 64), dim3(256), 0, stream,
                     ah, wt_out, out, C_DIM, C_DIM);
}